// Round 7
// baseline (168.731 us; speedup 1.0000x reference)
//
#include <hip/hip_runtime.h>
#include <math.h>

#define B_ 4
#define D_ 32
#define H_ 192
#define W_ 192
#define HW_ (H_ * W_)

#define NT 5            // Taylor terms p = 1..5

#define TW 48
#define TH 12
#define NTHR 256
#define ZCHUNK 16
#define NP (ZCHUNK + 8) // 24 staged planes; NP+1 pipelined iterations

#define XT_H 26         // TH + 14
#define XT_COLS 62      // TW + 14
#define XT_W 72         // %4==0 (b128-aligned rows)
#define XT_CELLS (XT_H * XT_COLS)   // 1612
#define NSEC 7

#define R_TS 28         // transposed R: [n][col][row], row stride 28 (%4==0)
#define CTERM (TW * R_TS)           // 1344 floats per term
#define RBUF (NT * CTERM)           // 6720 floats per buffer

#define XT_SZ (XT_H * XT_W)         // 1872
#define SMEM_WORDS (2 * XT_SZ + 2 * RBUF)   // 3744 + 13440 = 17184 (68.7 KB)

#define NTAPS (B_ * 9 * 15 * 15)

__device__ inline float4 f4fma(float c, float4 a, float4 d) {
    d.x = fmaf(c, a.x, d.x); d.y = fmaf(c, a.y, d.y);
    d.z = fmaf(c, a.z, d.z); d.w = fmaf(c, a.w, d.w);
    return d;
}
__device__ inline float rfl(float x) {
    return __int_as_float(__builtin_amdgcn_readfirstlane(__float_as_int(x)));
}

// Pipelined separable Taylor conv. One barrier per plane; R transposed
// ([n][col][row]) so h-conv reads 5 aligned b128 per term per 4 outputs.
__global__ __launch_bounds__(NTHR)
void conv_kernel(const float* __restrict__ x,
                 const float* __restrict__ bet_xy,
                 const float* __restrict__ bet_z,
                 const float* __restrict__ alpha,
                 float* __restrict__ out) {
    __shared__ __align__(16) float smem[SMEM_WORDS];
    float* xtb = smem;                 // [2][XT_SZ]
    float* Rb  = smem + 2 * XT_SZ;     // [2][NT][TW][R_TS]
    float* red = smem;                 // alias: pre-loop only
    float* ct  = smem + 512;           // alias: pre-loop only, [NT][16]

    const int t  = threadIdx.x;
    const int w0 = blockIdx.x * TW;
    const int h0 = blockIdx.y * TH;
    const int bz = blockIdx.z;
    const int b  = bz & 3;
    const int z0 = (bz >> 2) * ZCHUNK;
    const float INV = 0.3989422804014327f;

    // ---- exact global sum S (deterministic, identical in every block) ----
    float local = 0.f;
#pragma unroll
    for (int s = 0; s < 32; ++s) {
        int idx = t + s * NTHR;
        if (idx < NTAPS) {
            int bb = idx / 2025;
            int r  = idx % 2025;
            int dz = r / 225;
            int r2 = r % 225;
            int dh = r2 / 15;
            int dw = r2 % 15;
            float bxy = bet_xy[bb], bzv = bet_z[bb], al = alpha[bb];
            float zd = (float)(dz - 4), hd = (float)(dh - 7), wd = (float)(dw - 7);
            float az = expf(-zd * zd / (2.f * bzv * bzv)) * (INV / bzv);
            float gh = expf(-hd * hd / (2.f * bxy * bxy)) * (INV / bxy);
            float gw = expf(-wd * wd / (2.f * bxy * bxy)) * (INV / bxy);
            local += 1.f - expf(-al * az * gh * gw);
        }
    }
    red[t] = local;
    __syncthreads();
    for (int s = 128; s > 0; s >>= 1) {
        if (t < s) red[t] += red[t + s];
        __syncthreads();
    }
    const float S = red[0];
    __syncthreads();

    // ---- own batch's coefficient table (65 values) into LDS ----
    if (t < NT * 13) {
        int n = t / 13;
        int k = t % 13;
        float bxy = bet_xy[b], bzv = bet_z[b], al = alpha[b];
        if (k < 8) {
            float d = (float)k;
            float g = expf(-d * d / (2.f * bxy * bxy)) * (INV / bxy);
            float p = g;
            for (int q = 0; q < n; ++q) p *= g;
            ct[n * 16 + k] = p;
        } else {
            float d = (float)(k - 8);
            float az = expf(-d * d / (2.f * bzv * bzv)) * (INV / bzv);
            float base = al * az;
            float p = base;
            for (int q = 0; q < n; ++q) p *= base;
            const float facs[NT] = {1.f, 2.f, 6.f, 24.f, 120.f};
            float sign = (n & 1) ? -1.f : 1.f;
            ct[n * 16 + k] = sign * p / (facs[n] * S);
        }
    }
    __syncthreads();

    // ---- hoist coefficients to wave-uniform scalars (SGPRs) ----
    float cg_[NT][8], cz_[NT][5];
#pragma unroll
    for (int n = 0; n < NT; ++n) {
#pragma unroll
        for (int k = 0; k < 8; ++k) cg_[n][k] = rfl(ct[n * 16 + k]);
#pragma unroll
        for (int k = 0; k < 5; ++k) cz_[n][k] = rfl(ct[n * 16 + 8 + k]);
    }
    __syncthreads();   // ct/red reads done before xt staging overwrites alias

    // ---- staging descriptors (plane-invariant) ----
    const float* xb = x + (size_t)b * (D_ * HW_);
    int goff[NSEC], loff[NSEC];
#pragma unroll
    for (int k = 0; k < NSEC; ++k) {
        int i = t + k * NTHR;
        int r = i / XT_COLS, c = i - r * XT_COLS;
        int gh = h0 + r - 7, gw = w0 + c - 7;
        bool ok = (i < XT_CELLS) && gh >= 0 && gh < H_ && gw >= 0 && gw < W_;
        goff[k] = ok ? (gh * W_ + gw) : -1;
        loff[k] = (i < XT_CELLS) ? (r * XT_W + c) : (XT_SZ - 1);
    }
    // pre-stage first plane (zi = z0-4) into xt buffer 0
    {
        int zi0 = z0 - 4;
        if (zi0 >= 0) {
#pragma unroll
            for (int k = 0; k < NSEC; ++k) {
                float v = 0.f;
                if (goff[k] >= 0) v = xb[(size_t)zi0 * HW_ + goff[k]];
                xtb[loff[k]] = v;
            }
        }
    }

    // ---- per-thread roles ----
    // w items COLUMN-MAJOR over 26 rows x 12 colgroups (banks: 26 rows/wave)
    const int i0r = t % 26,  i0c = t / 26;             // item 0: all 256 threads
    const int i1  = t + 56;                            // item 1: t>=200 -> 256..311
    const int i1r = i1 % 26, i1c = i1 / 26;
    const bool sec1 = (t >= 200);
    const int wb0 = i0r * XT_W + 4 * i0c;
    const int rw0 = (4 * i0c) * R_TS + i0r;            // transposed write base
    const int wb1 = i1r * XT_W + 4 * i1c;
    const int rw1 = (4 * i1c) * R_TS + i1r;
    // h items TALL: t<144 -> col c (0..47), out rows 4q..4q+3
    const bool hact = (t < TW * 3);                    // 144
    const int hc = t % TW, hq = t / TW;
    const int r0 = 4 * hq;
    const int hb = hc * R_TS + r0;

    float4 acc[9];   // ring over z; float4 spans the 4 out-rows of this thread
#pragma unroll
    for (int k = 0; k < 9; ++k) acc[k] = make_float4(0.f, 0.f, 0.f, 0.f);

#pragma unroll 1
    for (int p = 0; p <= NP; ++p) {
        __syncthreads();   // xt[p&1] staged; R[(p-1)&1] complete; R[p&1] free

        const int zi = z0 - 4 + p;
        const bool do_w  = (p < NP) && (zi >= 0) && (zi < D_);
        const int  zn    = zi + 1;
        const bool pvalid = (p + 1 < NP) && (zn >= 0) && (zn < D_);

        // prefetch next plane into registers
        float pv[NSEC];
        if (pvalid) {
            const float* xp = xb + (size_t)zn * HW_;
#pragma unroll
            for (int k = 0; k < NSEC; ++k) pv[k] = (goff[k] >= 0) ? xp[goff[k]] : 0.f;
        }

        // ---- w-conv plane zi -> R[p&1] (transposed scatter writes) ----
        if (do_w) {
            const float* xt = xtb + (p & 1) * XT_SZ;
            float* Rw = Rb + (p & 1) * RBUF;
#pragma unroll
            for (int sec = 0; sec < 2; ++sec) {
                if (sec == 1 && !sec1) break;
                const int wb = sec ? wb1 : wb0;
                const int rw = sec ? rw1 : rw0;
                float win[20];
                {
                    const float4* p4 = (const float4*)&xt[wb];
#pragma unroll
                    for (int q = 0; q < 5; ++q) {
                        float4 a = p4[q];
                        win[4 * q] = a.x; win[4 * q + 1] = a.y;
                        win[4 * q + 2] = a.z; win[4 * q + 3] = a.w;
                    }
                }
                float cj[4], sp[4][7];
#pragma unroll
                for (int j = 0; j < 4; ++j) {
                    cj[j] = win[j + 7];
#pragma unroll
                    for (int k = 1; k <= 7; ++k) sp[j][k - 1] = win[j + 7 - k] + win[j + 7 + k];
                }
#pragma unroll
                for (int n = 0; n < NT; ++n) {
                    float a0 = cg_[n][0] * cj[0];
                    float a1 = cg_[n][0] * cj[1];
                    float a2 = cg_[n][0] * cj[2];
                    float a3 = cg_[n][0] * cj[3];
#pragma unroll
                    for (int k = 1; k <= 7; ++k) {
                        float c = cg_[n][k];
                        a0 = fmaf(c, sp[0][k - 1], a0);
                        a1 = fmaf(c, sp[1][k - 1], a1);
                        a2 = fmaf(c, sp[2][k - 1], a2);
                        a3 = fmaf(c, sp[3][k - 1], a3);
                    }
                    float* q = Rw + n * CTERM + rw;
                    q[0] = a0; q[R_TS] = a1; q[2 * R_TS] = a2; q[3 * R_TS] = a3;
                }
            }
        }

        // ---- h-conv plane p-1 from transposed R, z-accumulate, store ----
        if (p >= 1 && hact) {
            const int ziq = zi - 1;
            if (ziq >= 0 && ziq < D_) {
                const float* Rr = Rb + ((p - 1) & 1) * RBUF;
#pragma unroll
                for (int n = 0; n < NT; ++n) {
                    const float* R1 = Rr + n * CTERM + hb;
                    float v[20];
#pragma unroll
                    for (int k = 0; k < 5; ++k) {
                        float4 a = *(const float4*)&R1[4 * k];
                        v[4 * k] = a.x; v[4 * k + 1] = a.y;
                        v[4 * k + 2] = a.z; v[4 * k + 3] = a.w;
                    }
                    float4 q;
                    q.x = cg_[n][0] * v[7];
                    q.y = cg_[n][0] * v[8];
                    q.z = cg_[n][0] * v[9];
                    q.w = cg_[n][0] * v[10];
#pragma unroll
                    for (int m = 1; m <= 7; ++m) {
                        float c = cg_[n][m];
                        q.x = fmaf(c, v[7 - m]  + v[7 + m],  q.x);
                        q.y = fmaf(c, v[8 - m]  + v[8 + m],  q.y);
                        q.z = fmaf(c, v[9 - m]  + v[9 + m],  q.z);
                        q.w = fmaf(c, v[10 - m] + v[10 + m], q.w);
                    }
                    acc[4] = f4fma(cz_[n][0], q, acc[4]);
#pragma unroll
                    for (int j = 1; j <= 4; ++j) {
                        float cz = cz_[n][j];
                        acc[4 + j] = f4fma(cz, q, acc[4 + j]);
                        acc[4 - j] = f4fma(cz, q, acc[4 - j]);
                    }
                }
            }
            if (p - 1 >= 8) {
                int z = z0 + (p - 1 - 8);
                size_t o = ((size_t)(b * D_ + z) * H_ + (h0 + r0)) * W_ + (w0 + hc);
                out[o]          = acc[0].x;
                out[o + W_]     = acc[0].y;
                out[o + 2 * W_] = acc[0].z;
                out[o + 3 * W_] = acc[0].w;
            }
#pragma unroll
            for (int k = 0; k < 8; ++k) acc[k] = acc[k + 1];
            acc[8] = make_float4(0.f, 0.f, 0.f, 0.f);
        }

        // write prefetched plane into xt[(p+1)&1]
        if (pvalid) {
            float* xn = xtb + ((p + 1) & 1) * XT_SZ;
#pragma unroll
            for (int k = 0; k < NSEC; ++k) xn[loff[k]] = pv[k];
        }
    }
}

extern "C" void kernel_launch(void* const* d_in, const int* in_sizes, int n_in,
                              void* d_out, int out_size, void* d_ws, size_t ws_size,
                              hipStream_t stream) {
    const float* x      = (const float*)d_in[0];
    const float* bet_xy = (const float*)d_in[1];
    const float* bet_z  = (const float*)d_in[2];
    const float* alpha  = (const float*)d_in[3];
    float* out = (float*)d_out;

    hipLaunchKernelGGL(conv_kernel, dim3(W_ / TW, H_ / TH, B_ * (D_ / ZCHUNK)),
                       dim3(NTHR), 0, stream, x, bet_xy, bet_z, alpha, out);
}